// Round 1
// 101.925 us; speedup vs baseline: 1.0083x; 1.0083x over previous
//
#include <hip/hip_runtime.h>
#include <hip/hip_bf16.h>
#include <cstdint>

// Problem constants
#define NWORDS 16384   // B*S
#define NCH    20      // chars per word
#define CEDIM  32      // char emb dim
#define WEDIM  512     // output channels
#define WPB    32      // words per block
#define NBLK   (NWORDS/WPB)   // 512

typedef __attribute__((ext_vector_type(8)))  short bf16x8;
typedef __attribute__((ext_vector_type(16))) float f32x16;

__device__ __forceinline__ unsigned short f2bf(float f){
    union { float f; unsigned int u; } v; v.f = f;
    unsigned int u = v.u + 0x7fffu + ((v.u >> 16) & 1u);
    return (unsigned short)(u >> 16);
}

// Prep v4:
//  wbf3: B-frag layout for 32x32x16 (verified R8/R9), coalesced 1 KB per-wave loads:
//    idx = (((cc*8 + s)*2 + lh)*32 + col)*8 + j
//    value = bf16( W[o = cc*32+col][kk' = s*16 + lh*8 + j] )
//  cembbf: [256][32] bf16; bias[o] = sum_k cnn[o][32][k] (lang-bit row)
//  spidsT[c][w] = spelling[data[w]][c]  (R11: moves the scattered 2-level
//    gather out of conv's critical path into this latency-tolerant kernel;
//    conv then reads spidsT fully coalesced)
__global__ __launch_bounds__(256) void prep_kernel(const float* __restrict__ cnn,
                                                   const float* __restrict__ cemb,
                                                   const int* __restrict__ data,
                                                   const int* __restrict__ spelling,
                                                   unsigned short* __restrict__ wbf3,
                                                   unsigned short* __restrict__ cembbf,
                                                   float* __restrict__ bias,
                                                   int* __restrict__ spidsT){
    int idx = blockIdx.x * 256 + threadIdx.x;
    if (idx < 65536){
        int j   = idx & 7;
        int col = (idx >> 3) & 31;
        int lh  = (idx >> 8) & 1;
        int s   = (idx >> 9) & 7;
        int cc  = idx >> 12;
        int o   = cc*32 + col;
        int kk  = s*16 + lh*8 + j;
        int i   = kk & 31, k = kk >> 5;
        wbf3[idx] = f2bf(cnn[o*132 + i*4 + k]);
    } else if (idx < 65536 + 256*CEDIM){
        int r = idx - 65536;
        cembbf[r] = f2bf(cemb[r]);
    } else if (idx < 65536 + 256*CEDIM + WEDIM){
        int o = idx - (65536 + 256*CEDIM);
        const float* p = cnn + o*132 + 128;
        bias[o] = p[0] + p[1] + p[2] + p[3];
    } else if (idx < 65536 + 256*CEDIM + WEDIM + NWORDS){
        int w  = idx - (65536 + 256*CEDIM + WEDIM);
        int wd = data[w];
        // spelling row: 20 ints = 80 B = 5 x int4 (16B-aligned since 80%16==0)
        const int4* sp = reinterpret_cast<const int4*>(spelling + wd*NCH);
        int4 v0 = sp[0], v1 = sp[1], v2 = sp[2], v3 = sp[3], v4 = sp[4];
        int vals[20] = { v0.x,v0.y,v0.z,v0.w, v1.x,v1.y,v1.z,v1.w,
                         v2.x,v2.y,v2.z,v2.w, v3.x,v3.y,v3.z,v3.w,
                         v4.x,v4.y,v4.z,v4.w };
        #pragma unroll
        for (int c = 0; c < NCH; ++c)
            spidsT[c*NWORDS + w] = vals[c];   // coalesced across lanes per c
    }
}

// Round 11: same verified t-major 32x32x16 compute loop as R10, restructured
// for CU-level overlap:
//  - 256-thread (4-wave) blocks, still 32 words x all 512 cols (4 col passes
//    per wave). At the same register budget this lets 2-3 blocks co-reside
//    per CU (vs 1 with 512-thread blocks), so one block's stage/B-load/
//    epilogue bubbles hide under another block's MFMA stream.
//  - staging via global_load_lds width-16: linear LDS dest (wave-uniform
//    base + lane*16, two 512B (c,q) chunks per wave-issue), per-lane global
//    src = cembbf + id*64 + q*16. spid reads are coalesced from spidsT.
//    Removes the VGPR round-trip and 2 levels of the dependent gather chain.
// waves_per_eu(2) kept: it is a compiler floor, not a cap — if natural VGPR
// use lands <=170 we get 3 blocks/CU for free, with zero spill risk.
__global__ __attribute__((amdgpu_waves_per_eu(2))) __launch_bounds__(256)
void conv_kernel(
    const int* __restrict__ spids,             // [20][16384]
    const unsigned short* __restrict__ cembbf, // [256][32] bf16
    const unsigned short* __restrict__ wbf3,   // [16][8][2][32][8] bf16
    const float* __restrict__ bias,            // [512]
    float* __restrict__ out)                   // [16384][512] f32
{
    // sA[c][q][word] : 16B frag = cembbf[id(word,c)][ bytes q*16.. ]
    __shared__ __align__(16) char sA[20*4*32*16];   // 40960 B

    const int tid  = threadIdx.x;
    const int wv   = tid >> 6;        // wave 0..3
    const int lane = tid & 63;
    const int ln31 = lane & 31;       // A row (word) / C-D col offset
    const int lh   = lane >> 5;
    const int wbase = blockIdx.x * WPB;

    // ---- staging: 80 (c,q)-chunks x 32 words = 40960 B via global_load_lds.
    // Wave-issue pp covers chunks cq=2pp (lanes 0-31) and 2pp+1 (lanes 32-63):
    // both halves share c = (2pp+lh)>>2, q = (2pp+lh)&3. 10 issues per wave.
    {
        int ids[10];
        #pragma unroll
        for (int n = 0; n < 10; ++n){
            int cq = 2*(wv + 4*n) + lh;
            ids[n] = spids[(cq >> 2)*NWORDS + wbase + ln31];  // coalesced 128B
        }
        #pragma unroll
        for (int n = 0; n < 10; ++n){
            int pp = wv + 4*n;                    // pair index 0..39
            int q  = (2*pp + lh) & 3;
            const char* src = (const char*)cembbf + (ids[n] << 6) + (q << 4);
            __builtin_amdgcn_global_load_lds(
                (const __attribute__((address_space(1))) unsigned int*)src,
                (__attribute__((address_space(3))) unsigned int*)(sA + (pp << 10)),
                16, 0, 0);
        }
    }
    __syncthreads();   // drains vmcnt incl. global_load_lds

    const char* wb = (const char*)wbf3;

    // A-frag via LDS: lane holds A[m=ln31][kk'=s*16+lh*8+j], char c, half p=s&1
    auto ldA = [&](int c, int p) -> bf16x8 {
        return *reinterpret_cast<const bf16x8*>(
            sA + ((c*4 + p*2 + lh) << 9) + (ln31 << 4));
    };

    f32x16 zz;
    #pragma unroll
    for (int r = 0; r < 16; ++r) zz[r] = 0.f;

    #pragma unroll 1
    for (int half = 0; half < 4; ++half){
        const int cc16 = wv + half*4;     // 32-col chunk 0..15
        const int colb = cc16*32;

        // B-frags for all 8 K-steps: 1 KB coalesced loads, reused 17x (L2-hot)
        const char* wbb = wb + cc16*8192 + lane*16;
        bf16x8 bs[8];
        #pragma unroll
        for (int s = 0; s < 8; ++s)
            bs[s] = *reinterpret_cast<const bf16x8*>(wbb + s*1024);

        // sliding A window: chars t..t+3, two i-halves each
        bf16x8 aw[4][2];
        #pragma unroll
        for (int c = 0; c < 4; ++c){
            aw[c][0] = ldA(c, 0);
            aw[c][1] = ldA(c, 1);
        }

        f32x16 vmax;
        #pragma unroll
        for (int t = 0; t < 17; ++t){
            f32x16 acc;
            acc = __builtin_amdgcn_mfma_f32_32x32x16_bf16(aw[ t   &3][0], bs[0], zz,  0,0,0);
            acc = __builtin_amdgcn_mfma_f32_32x32x16_bf16(aw[ t   &3][1], bs[1], acc, 0,0,0);
            acc = __builtin_amdgcn_mfma_f32_32x32x16_bf16(aw[(t+1)&3][0], bs[2], acc, 0,0,0);
            acc = __builtin_amdgcn_mfma_f32_32x32x16_bf16(aw[(t+1)&3][1], bs[3], acc, 0,0,0);
            acc = __builtin_amdgcn_mfma_f32_32x32x16_bf16(aw[(t+2)&3][0], bs[4], acc, 0,0,0);
            acc = __builtin_amdgcn_mfma_f32_32x32x16_bf16(aw[(t+2)&3][1], bs[5], acc, 0,0,0);
            acc = __builtin_amdgcn_mfma_f32_32x32x16_bf16(aw[(t+3)&3][0], bs[6], acc, 0,0,0);
            acc = __builtin_amdgcn_mfma_f32_32x32x16_bf16(aw[(t+3)&3][1], bs[7], acc, 0,0,0);

            if (t == 0){
                vmax = acc;
            } else {
                #pragma unroll
                for (int r = 0; r < 16; ++r) vmax[r] = fmaxf(vmax[r], acc[r]);
            }
            if (t < 16){
                aw[t&3][0] = ldA(t+4, 0);
                aw[t&3][1] = ldA(t+4, 1);
            }
        }

        // ---- epilogue: direct stores, no shuffles ----
        // C/D: col = colb + ln31, row(word) = (r&3) + 8*(r>>2) + 4*lh
        float bv = bias[colb + ln31];
        #pragma unroll
        for (int r = 0; r < 16; ++r){
            int row = (r & 3) + 8*(r >> 2) + 4*lh;
            __builtin_nontemporal_store(vmax[r] + bv,
                out + (wbase + row)*WEDIM + colb + ln31);
        }
    }
}

extern "C" void kernel_launch(void* const* d_in, const int* in_sizes, int n_in,
                              void* d_out, int out_size, void* d_ws, size_t ws_size,
                              hipStream_t stream) {
    const float* cemb     = (const float*)d_in[0];   // char_emb_w [256*32]
    const float* cnn      = (const float*)d_in[1];   // cnn_w [512*33*4]
    const int*   data     = (const int*)d_in[2];     // [16384]
    const int*   spelling = (const int*)d_in[3];     // [50000*20]
    float* outp = (float*)d_out;

    unsigned short* wbf3   = (unsigned short*)d_ws;                       // 131072 B
    float*          bias   = (float*)((char*)d_ws + 131072);              // 2048 B
    unsigned short* cembbf = (unsigned short*)((char*)d_ws + 133120);     // 16384 B
    int*            spids  = (int*)((char*)d_ws + 149504);                // 1310720 B

    int prep_items = 65536 + 256*CEDIM + WEDIM + NWORDS;   // 90624
    prep_kernel<<<dim3((prep_items + 255)/256), dim3(256), 0, stream>>>(
        cnn, cemb, data, spelling, wbf3, cembbf, bias, spids);
    conv_kernel<<<dim3(NBLK), dim3(256), 0, stream>>>(spids, cembbf, wbf3, bias, outp);
}